// Round 2
// baseline (12791.431 us; speedup 1.0000x reference)
//
#include <hip/hip_runtime.h>

#define TT 1024
#define CC 1024
#define HH 16
#define DHH 64
#define BB 4
#define LL 8
#define FFF 4096
#define MM (BB*TT)   // 4096 rows

// ---------------------------------------------------------------------------
// LayerNorm: one block per row (1024 elems, 256 threads x float4)
// ---------------------------------------------------------------------------
__global__ __launch_bounds__(256) void ln_k(const float* __restrict__ x,
                                            const float* __restrict__ w,
                                            const float* __restrict__ b,
                                            float* __restrict__ o) {
  int row = blockIdx.x;
  int tid = threadIdx.x;
  const float* xr = x + (size_t)row * CC;
  float4 v = ((const float4*)xr)[tid];
  float s = v.x + v.y + v.z + v.w;
#pragma unroll
  for (int m = 1; m < 64; m <<= 1) s += __shfl_xor(s, m, 64);
  __shared__ float r1[4];
  __shared__ float r2[4];
  if ((tid & 63) == 0) r1[tid >> 6] = s;
  __syncthreads();
  float mu = (r1[0] + r1[1] + r1[2] + r1[3]) * (1.0f / CC);
  float d0 = v.x - mu, d1 = v.y - mu, d2 = v.z - mu, d3 = v.w - mu;
  float sq = d0 * d0 + d1 * d1 + d2 * d2 + d3 * d3;
#pragma unroll
  for (int m = 1; m < 64; m <<= 1) sq += __shfl_xor(sq, m, 64);
  if ((tid & 63) == 0) r2[tid >> 6] = sq;
  __syncthreads();
  float var = (r2[0] + r2[1] + r2[2] + r2[3]) * (1.0f / CC);
  float rs = rsqrtf(var + 1e-5f);
  float4 wv = ((const float4*)w)[tid];
  float4 bv = ((const float4*)b)[tid];
  float4 ov;
  ov.x = d0 * rs * wv.x + bv.x;
  ov.y = d1 * rs * wv.y + bv.y;
  ov.z = d2 * rs * wv.z + bv.z;
  ov.w = d3 * rs * wv.w + bv.w;
  ((float4*)(o + (size_t)row * CC))[tid] = ov;
}

// ---------------------------------------------------------------------------
// fp32 tiled GEMM body: 128x128 tile, BK=16, 256 threads, 8x8/thread.
// Register-prefetch double buffering: next tile's global loads are issued
// before the compute loop so HBM/L2 latency hides under the 1024 FMAs.
// EPI: 0 = +bias ; 1 = +bias+residual ; 2 = gelu(+bias)
// ---------------------------------------------------------------------------
#define BK 16
#define LDT 132  // padded LDS stride (floats): hot reads <=2-way conflict (free)

__device__ __forceinline__ float gelu_f(float x) {
  return 0.5f * x * (1.0f + erff(x * 0.70710678118654752f));
}

template <int EPI>
__device__ __forceinline__ void gemm_body(const float* __restrict__ A,
                                          const float* __restrict__ Bw,
                                          const float* __restrict__ bias,
                                          const float* __restrict__ res,
                                          float* __restrict__ C,
                                          int M, int N, int K,
                                          int m0, int n0,
                                          float (*As)[LDT], float (*Bs)[LDT]) {
  int tid = threadIdx.x;
  int tx = tid & 15, ty = tid >> 4;

  int ar = tid >> 1;            // A row within tile (0..127)
  int aslot = (tid & 1) * 2;    // which pair of float4 k-slots
  int brow = tid >> 4;          // B row within tile (0..15)
  int bslot = (tid & 15) * 2;   // which pair of float4 col-slots

  const float* Aptr = A + (size_t)(m0 + ar) * K;
  const float* Bptr = Bw + (size_t)brow * N + n0;

  float4 ra0 = ((const float4*)Aptr)[aslot];
  float4 ra1 = ((const float4*)Aptr)[aslot + 1];
  float4 rb0 = ((const float4*)Bptr)[bslot];
  float4 rb1 = ((const float4*)Bptr)[bslot + 1];

  float acc[2][2][4][4] = {};

  for (int k0 = 0; k0 < K; k0 += BK) {
    // stage current regs -> LDS
    int ka = aslot * 4;
    As[ka + 0][ar] = ra0.x; As[ka + 1][ar] = ra0.y;
    As[ka + 2][ar] = ra0.z; As[ka + 3][ar] = ra0.w;
    As[ka + 4][ar] = ra1.x; As[ka + 5][ar] = ra1.y;
    As[ka + 6][ar] = ra1.z; As[ka + 7][ar] = ra1.w;
    *(float4*)&Bs[brow][bslot * 4] = rb0;
    *(float4*)&Bs[brow][bslot * 4 + 4] = rb1;
    __syncthreads();

    // prefetch next tile (latency hidden under compute below)
    if (k0 + BK < K) {
      const float* An = Aptr + k0 + BK;
      ra0 = ((const float4*)An)[aslot];
      ra1 = ((const float4*)An)[aslot + 1];
      const float* Bn = Bptr + (size_t)(k0 + BK) * N;
      rb0 = ((const float4*)Bn)[bslot];
      rb1 = ((const float4*)Bn)[bslot + 1];
    }

#pragma unroll
    for (int kk = 0; kk < BK; ++kk) {
      float4 av0 = *(const float4*)&As[kk][ty * 4];
      float4 av1 = *(const float4*)&As[kk][ty * 4 + 64];
      float4 bv0 = *(const float4*)&Bs[kk][tx * 4];
      float4 bv1 = *(const float4*)&Bs[kk][tx * 4 + 64];
      float aa[2][4] = {{av0.x, av0.y, av0.z, av0.w},
                        {av1.x, av1.y, av1.z, av1.w}};
      float bb[2][4] = {{bv0.x, bv0.y, bv0.z, bv0.w},
                        {bv1.x, bv1.y, bv1.z, bv1.w}};
#pragma unroll
      for (int p = 0; p < 2; ++p)
#pragma unroll
        for (int i = 0; i < 4; ++i)
#pragma unroll
          for (int q = 0; q < 2; ++q)
#pragma unroll
            for (int j = 0; j < 4; ++j)
              acc[p][q][i][j] = fmaf(aa[p][i], bb[q][j], acc[p][q][i][j]);
    }
    __syncthreads();  // LDS free for next stage
  }

#pragma unroll
  for (int p = 0; p < 2; ++p) {
#pragma unroll
    for (int i = 0; i < 4; ++i) {
      size_t gr = (size_t)(m0 + p * 64 + ty * 4 + i);
      float* Crow = C + gr * N + n0;
#pragma unroll
      for (int q = 0; q < 2; ++q) {
        int c = q * 64 + tx * 4;
        float4 bvv = *(const float4*)&bias[n0 + c];
        float4 o;
        o.x = acc[p][q][i][0] + bvv.x;
        o.y = acc[p][q][i][1] + bvv.y;
        o.z = acc[p][q][i][2] + bvv.z;
        o.w = acc[p][q][i][3] + bvv.w;
        if (EPI == 2) {
          o.x = gelu_f(o.x); o.y = gelu_f(o.y);
          o.z = gelu_f(o.z); o.w = gelu_f(o.w);
        }
        if (EPI == 1) {
          const float* Rrow = res + gr * N + n0;
          float4 rv = *(const float4*)&Rrow[c];
          o.x += rv.x; o.y += rv.y; o.z += rv.z; o.w += rv.w;
        }
        *(float4*)&Crow[c] = o;
      }
    }
  }
}

template <int EPI>
__global__ __launch_bounds__(256) void gemm_k(const float* __restrict__ A,
                                              const float* __restrict__ Bw,
                                              const float* __restrict__ bias,
                                              const float* __restrict__ res,
                                              float* __restrict__ C,
                                              int M, int N, int K) {
  __shared__ float As[BK][LDT];
  __shared__ float Bs[BK][LDT];
  gemm_body<EPI>(A, Bw, bias, res, C, M, N, K,
                 blockIdx.y * 128, blockIdx.x * 128, As, Bs);
}

// Fused QKV: grid.x = 24; blockIdx.x>>3 selects {wq,wk,wv}. 768 blocks
// = 3 blocks/CU (vs 1 for separate launches) -> latency hiding + L2 A-reuse.
__global__ __launch_bounds__(256) void qkv_k(const float* __restrict__ A,
                                             const float* __restrict__ wq,
                                             const float* __restrict__ wk,
                                             const float* __restrict__ wv,
                                             const float* __restrict__ bq,
                                             const float* __restrict__ bk,
                                             const float* __restrict__ bv,
                                             float* __restrict__ qo,
                                             float* __restrict__ ko,
                                             float* __restrict__ vo) {
  __shared__ float As[BK][LDT];
  __shared__ float Bs[BK][LDT];
  int which = blockIdx.x >> 3;
  int n0 = (blockIdx.x & 7) * 128;
  const float* Bw = (which == 0) ? wq : (which == 1) ? wk : wv;
  const float* bias = (which == 0) ? bq : (which == 1) ? bk : bv;
  float* C = (which == 0) ? qo : (which == 1) ? ko : vo;
  gemm_body<0>(A, Bw, bias, nullptr, C, MM, CC, CC, blockIdx.y * 128, n0, As, Bs);
}

// ---------------------------------------------------------------------------
// Fused masked attention, flash-style. One block = 64 q-rows of one (b,h).
// Mask computed analytically (matches _build_mask exactly):
//   keep = (j<=i) || (i<1023 && i/10==j/10 && j%10<=8)
// => k extends at most 9 past i => k-blocks <= qb+1.
// ---------------------------------------------------------------------------
__global__ __launch_bounds__(256) void attn_k(const float* __restrict__ q,
                                              const float* __restrict__ k,
                                              const float* __restrict__ v,
                                              float* __restrict__ y) {
  __shared__ float Qs[64][65];
  __shared__ float KPs[64][65];  // K tile, then reused as P tile
  __shared__ float Vs[64][64];

  int tid = threadIdx.x;
  int tx = tid & 15, ty = tid >> 4;
  int qb = blockIdx.x;
  int bh = blockIdx.y;
  int b = bh >> 4;   // H = 16
  int h = bh & 15;
  int q0 = qb * 64;

  const float* qbase = q + (size_t)b * TT * CC + (size_t)h * DHH;
  const float* kbase = k + (size_t)b * TT * CC + (size_t)h * DHH;
  const float* vbase = v + (size_t)b * TT * CC + (size_t)h * DHH;

#pragma unroll
  for (int i = 0; i < 4; ++i) {
    int r = ty + 16 * i;
    float4 t = *(const float4*)(qbase + (size_t)(q0 + r) * CC + tx * 4);
    Qs[r][tx * 4 + 0] = t.x; Qs[r][tx * 4 + 1] = t.y;
    Qs[r][tx * 4 + 2] = t.z; Qs[r][tx * 4 + 3] = t.w;
  }

  float mrun[4], lrun[4], accO[4][4];
#pragma unroll
  for (int i = 0; i < 4; ++i) {
    mrun[i] = -1e30f; lrun[i] = 0.0f;
#pragma unroll
    for (int j = 0; j < 4; ++j) accO[i][j] = 0.0f;
  }

  int kbmax = qb + 1; if (kbmax > (TT / 64 - 1)) kbmax = TT / 64 - 1;
  for (int kb = 0; kb <= kbmax; ++kb) {
    int k0 = kb * 64;
    __syncthreads();  // prev iter done with KPs/Vs (Qs visible iter 0)
#pragma unroll
    for (int i = 0; i < 4; ++i) {
      int r = ty + 16 * i;
      float4 tk = *(const float4*)(kbase + (size_t)(k0 + r) * CC + tx * 4);
      KPs[r][tx * 4 + 0] = tk.x; KPs[r][tx * 4 + 1] = tk.y;
      KPs[r][tx * 4 + 2] = tk.z; KPs[r][tx * 4 + 3] = tk.w;
      float4 tv = *(const float4*)(vbase + (size_t)(k0 + r) * CC + tx * 4);
      *(float4*)&Vs[r][tx * 4] = tv;
    }
    __syncthreads();

    // S = (Q K^T) * scale, masked (analytic mask)
    float s[4][4] = {};
    for (int d = 0; d < 64; ++d) {
      float qv[4], kv[4];
#pragma unroll
      for (int i = 0; i < 4; ++i) qv[i] = Qs[ty * 4 + i][d];
#pragma unroll
      for (int j = 0; j < 4; ++j) kv[j] = KPs[tx * 4 + j][d];
#pragma unroll
      for (int i = 0; i < 4; ++i)
#pragma unroll
        for (int j = 0; j < 4; ++j)
          s[i][j] = fmaf(qv[i], kv[j], s[i][j]);
    }
#pragma unroll
    for (int i = 0; i < 4; ++i) {
      int gi = q0 + ty * 4 + i;
#pragma unroll
      for (int j = 0; j < 4; ++j) {
        int gj = k0 + tx * 4 + j;
        bool keep = (gj <= gi) ||
                    ((gi < TT - 1) && (gi / 10 == gj / 10) && (gj % 10 <= 8));
        s[i][j] = keep ? s[i][j] * 0.125f : -1e30f;
      }
    }
    __syncthreads();  // all lanes done reading K tile before P overwrites it

    // online softmax (each row owned by the 16 lanes sharing ty)
#pragma unroll
    for (int i = 0; i < 4; ++i) {
      float mloc = fmaxf(fmaxf(s[i][0], s[i][1]), fmaxf(s[i][2], s[i][3]));
#pragma unroll
      for (int m = 1; m < 16; m <<= 1) mloc = fmaxf(mloc, __shfl_xor(mloc, m, 64));
      float mnew = fmaxf(mrun[i], mloc);
      float p0 = __expf(s[i][0] - mnew);
      float p1 = __expf(s[i][1] - mnew);
      float p2 = __expf(s[i][2] - mnew);
      float p3 = __expf(s[i][3] - mnew);
      float psum = p0 + p1 + p2 + p3;
#pragma unroll
      for (int m = 1; m < 16; m <<= 1) psum += __shfl_xor(psum, m, 64);
      float alpha = __expf(mrun[i] - mnew);
      lrun[i] = lrun[i] * alpha + psum;
      mrun[i] = mnew;
#pragma unroll
      for (int j = 0; j < 4; ++j) accO[i][j] *= alpha;
      KPs[ty * 4 + i][tx * 4 + 0] = p0;
      KPs[ty * 4 + i][tx * 4 + 1] = p1;
      KPs[ty * 4 + i][tx * 4 + 2] = p2;
      KPs[ty * 4 + i][tx * 4 + 3] = p3;
    }
    __syncthreads();  // P visible

    // O += P V
    for (int c = 0; c < 64; ++c) {
      float pr[4];
#pragma unroll
      for (int i = 0; i < 4; ++i) pr[i] = KPs[ty * 4 + i][c];
      float4 vv = *(const float4*)&Vs[c][tx * 4];
      float vb4[4] = {vv.x, vv.y, vv.z, vv.w};
#pragma unroll
      for (int i = 0; i < 4; ++i)
#pragma unroll
        for (int j = 0; j < 4; ++j)
          accO[i][j] = fmaf(pr[i], vb4[j], accO[i][j]);
    }
  }

#pragma unroll
  for (int i = 0; i < 4; ++i) {
    float inv = 1.0f / lrun[i];
    float4 o;
    o.x = accO[i][0] * inv; o.y = accO[i][1] * inv;
    o.z = accO[i][2] * inv; o.w = accO[i][3] * inv;
    *(float4*)(y + (size_t)(b * TT + q0 + ty * 4 + i) * CC + h * DHH + tx * 4) = o;
  }
}

// ---------------------------------------------------------------------------
extern "C" void kernel_launch(void* const* d_in, const int* in_sizes, int n_in,
                              void* d_out, int out_size, void* d_ws, size_t ws_size,
                              hipStream_t stream) {
  (void)in_sizes; (void)n_in; (void)out_size;
  const float* x    = (const float*)d_in[0];
  const float* ln1w = (const float*)d_in[1];
  const float* ln1b = (const float*)d_in[2];
  const float* ln2w = (const float*)d_in[3];
  const float* ln2b = (const float*)d_in[4];
  const float* wq   = (const float*)d_in[5];
  const float* bq   = (const float*)d_in[6];
  const float* wk   = (const float*)d_in[7];
  const float* bk   = (const float*)d_in[8];
  const float* wv   = (const float*)d_in[9];
  const float* bv   = (const float*)d_in[10];
  const float* wo   = (const float*)d_in[11];
  const float* bo   = (const float*)d_in[12];
  const float* w1   = (const float*)d_in[13];
  const float* b1   = (const float*)d_in[14];
  const float* w2   = (const float*)d_in[15];
  const float* b2   = (const float*)d_in[16];
  float* out = (float*)d_out;

  const size_t SZ = (size_t)MM * CC;  // 4M floats (16 MB)
  float* hbuf = (float*)d_ws;
  float* qbuf = hbuf + SZ;
  float* kbuf = qbuf + SZ;
  float* vbuf = kbuf + SZ;

  // MLP hidden: own buffer if ws allows (128 MB total), else reuse dead
  // q/k/v region in 2 chunks (64 MB total requirement).
  float* hid;
  int nch;
  if (ws_size >= (4 * SZ + (size_t)MM * FFF) * sizeof(float)) {
    hid = vbuf + SZ; nch = 1;
  } else {
    hid = qbuf; nch = 2;  // 2048*4096*4 = 32 MB fits in q/k/v's 48 MB
  }
  int mch = MM / nch;

  // residual stream lives in d_out
  hipMemcpyAsync(out, x, SZ * sizeof(float), hipMemcpyDeviceToDevice, stream);

  dim3 gProj(CC / 128, MM / 128);  // (8, 32)

  for (int l = 0; l < LL; ++l) {
    const float* wq_l = wq + (size_t)l * CC * CC;
    const float* wk_l = wk + (size_t)l * CC * CC;
    const float* wv_l = wv + (size_t)l * CC * CC;
    const float* wo_l = wo + (size_t)l * CC * CC;
    const float* w1_l = w1 + (size_t)l * CC * FFF;
    const float* w2_l = w2 + (size_t)l * FFF * CC;

    ln_k<<<MM, 256, 0, stream>>>(out, ln1w + (size_t)l * CC, ln1b + (size_t)l * CC, hbuf);
    qkv_k<<<dim3(24, MM / 128), 256, 0, stream>>>(
        hbuf, wq_l, wk_l, wv_l,
        bq + (size_t)l * CC, bk + (size_t)l * CC, bv + (size_t)l * CC,
        qbuf, kbuf, vbuf);
    attn_k<<<dim3(TT / 64, BB * HH), 256, 0, stream>>>(qbuf, kbuf, vbuf, hbuf);
    gemm_k<1><<<gProj, 256, 0, stream>>>(hbuf, wo_l, bo + (size_t)l * CC, out, out, MM, CC, CC);
    ln_k<<<MM, 256, 0, stream>>>(out, ln2w + (size_t)l * CC, ln2b + (size_t)l * CC, hbuf);
    for (int c = 0; c < nch; ++c) {
      const float* aoff = hbuf + (size_t)c * mch * CC;
      float* ooff = out + (size_t)c * mch * CC;
      gemm_k<2><<<dim3(FFF / 128, mch / 128), 256, 0, stream>>>(
          aoff, w1_l, b1 + (size_t)l * FFF, nullptr, hid, mch, FFF, CC);
      gemm_k<1><<<dim3(CC / 128, mch / 128), 256, 0, stream>>>(
          hid, w2_l, b2 + (size_t)l * CC, ooff, ooff, mch, CC, FFF);
    }
  }
}

// Round 4
// 6003.950 us; speedup vs baseline: 2.1305x; 2.1305x over previous
//
#include <hip/hip_runtime.h>

#define TT 1024
#define CC 1024
#define HH 16
#define DHH 64
#define BB 4
#define LL 8
#define FFF 4096
#define MM (BB*TT)   // 4096 rows

typedef float f32x4 __attribute__((ext_vector_type(4)));
typedef short s16x8 __attribute__((ext_vector_type(8)));
typedef unsigned short u16x8 __attribute__((ext_vector_type(8)));
typedef unsigned short u16x4 __attribute__((ext_vector_type(4)));

__device__ __forceinline__ unsigned short f2bf(float x) {
  unsigned int u = __float_as_uint(x);
  unsigned int r = u + 0x7FFFu + ((u >> 16) & 1u);   // RNE
  return (unsigned short)(r >> 16);
}
__device__ __forceinline__ float bf2f(unsigned short h) {
  return __uint_as_float(((unsigned int)h) << 16);
}
__device__ __forceinline__ float gelu_f(float x) {
  return 0.5f * x * (1.0f + erff(x * 0.70710678118654752f));
}

// ---------------------------------------------------------------------------
// Weight split+TRANSPOSE kernel: W[K][N] fp32 -> Wt_hi/Wt_lo[N][K] bf16 bits.
// 64x64 tiles staged through LDS; coalesced global reads AND writes.
// Regions: 0..3 = wq,wk,wv,wo (1024x1024); 4 = w1 (1024x4096); 5 = w2 (4096x1024).
// Tile index ranges: r<4: 256 tiles each; r4: 1024; r5: 1024.  Total 3072.
// ---------------------------------------------------------------------------
struct SplitArgs {
  const float* src[6];
  unsigned short* dh[6];
  unsigned short* dl[6];
};

__global__ __launch_bounds__(256) void splitT_k(SplitArgs a) {
  __shared__ float Ls[64][65];
  int idx = blockIdx.x;
  int r, t;
  if (idx < 1024)      { r = idx >> 8; t = idx & 255; }
  else if (idx < 2048) { r = 4; t = idx - 1024; }
  else                 { r = 5; t = idx - 2048; }
  int K = (r == 5) ? FFF : CC;
  int N = (r == 4) ? FFF : CC;
  int Nt = N >> 6;
  int k0 = (t / Nt) * 64, n0 = (t % Nt) * 64;

  const float* s = a.src[r];
  int tid = threadIdx.x;
  int rrow = tid >> 4, rcol = tid & 15;
#pragma unroll
  for (int i = 0; i < 4; ++i) {
    int rl = rrow + 16 * i;
    float4 v = *(const float4*)(s + (size_t)(k0 + rl) * N + n0 + rcol * 4);
    Ls[rl][rcol * 4 + 0] = v.x; Ls[rl][rcol * 4 + 1] = v.y;
    Ls[rl][rcol * 4 + 2] = v.z; Ls[rl][rcol * 4 + 3] = v.w;
  }
  __syncthreads();

  int nl = tid >> 2, ks = (tid & 3) * 16;
  u16x8 h0, h1, l0, l1;
#pragma unroll
  for (int j = 0; j < 8; ++j) {
    float f = Ls[ks + j][nl];
    h0[j] = f2bf(f); l0[j] = f2bf(f - bf2f(h0[j]));
  }
#pragma unroll
  for (int j = 0; j < 8; ++j) {
    float f = Ls[ks + 8 + j][nl];
    h1[j] = f2bf(f); l1[j] = f2bf(f - bf2f(h1[j]));
  }
  size_t o = (size_t)(n0 + nl) * K + k0 + ks;
  *(u16x8*)(a.dh[r] + o) = h0; *(u16x8*)(a.dh[r] + o + 8) = h1;
  *(u16x8*)(a.dl[r] + o) = l0; *(u16x8*)(a.dl[r] + o + 8) = l1;
}

// ---------------------------------------------------------------------------
// LayerNorm. OUT=0: fp32 out. OUT=1: split bf16 hi/lo out.
// ---------------------------------------------------------------------------
template <int OUT>
__global__ __launch_bounds__(256) void ln_k(const float* __restrict__ x,
                                            const float* __restrict__ w,
                                            const float* __restrict__ b,
                                            float* __restrict__ of,
                                            unsigned short* __restrict__ oh,
                                            unsigned short* __restrict__ ol) {
  int row = blockIdx.x;
  int tid = threadIdx.x;
  const float* xr = x + (size_t)row * CC;
  float4 v = ((const float4*)xr)[tid];
  float s = v.x + v.y + v.z + v.w;
#pragma unroll
  for (int m = 1; m < 64; m <<= 1) s += __shfl_xor(s, m, 64);
  __shared__ float r1[4];
  __shared__ float r2[4];
  if ((tid & 63) == 0) r1[tid >> 6] = s;
  __syncthreads();
  float mu = (r1[0] + r1[1] + r1[2] + r1[3]) * (1.0f / CC);
  float d0 = v.x - mu, d1 = v.y - mu, d2 = v.z - mu, d3 = v.w - mu;
  float sq = d0 * d0 + d1 * d1 + d2 * d2 + d3 * d3;
#pragma unroll
  for (int m = 1; m < 64; m <<= 1) sq += __shfl_xor(sq, m, 64);
  if ((tid & 63) == 0) r2[tid >> 6] = sq;
  __syncthreads();
  float var = (r2[0] + r2[1] + r2[2] + r2[3]) * (1.0f / CC);
  float rs = rsqrtf(var + 1e-5f);
  float4 wv = ((const float4*)w)[tid];
  float4 bv = ((const float4*)b)[tid];
  float o0 = d0 * rs * wv.x + bv.x;
  float o1 = d1 * rs * wv.y + bv.y;
  float o2 = d2 * rs * wv.z + bv.z;
  float o3 = d3 * rs * wv.w + bv.w;
  if (OUT == 0) {
    float4 ov; ov.x = o0; ov.y = o1; ov.z = o2; ov.w = o3;
    ((float4*)(of + (size_t)row * CC))[tid] = ov;
  } else {
    u16x4 h, lo;
    h[0] = f2bf(o0); lo[0] = f2bf(o0 - bf2f(h[0]));
    h[1] = f2bf(o1); lo[1] = f2bf(o1 - bf2f(h[1]));
    h[2] = f2bf(o2); lo[2] = f2bf(o2 - bf2f(h[2]));
    h[3] = f2bf(o3); lo[3] = f2bf(o3 - bf2f(h[3]));
    *(u16x4*)(oh + (size_t)row * CC + tid * 4) = h;
    *(u16x4*)(ol + (size_t)row * CC + tid * 4) = lo;
  }
}

// ---------------------------------------------------------------------------
// Split-bf16 MFMA GEMM. Both operands [row][K] (weights pre-transposed).
// 128x128 tile, BK=32, 4 waves (2x2), wave tile 64x64 = 4x4 x 16x16x32 MFMA.
// 3 MFMAs per k-frag pair: hh + lo_a*hi_b + hi_a*lo_b.
// Staging: pure b128 load->store, no scatter. LDA=40 pad (frag reads ~2-way).
// EPI: 0 = +bias (fp32 out); 1 = +bias+res (fp32 out); 2 = gelu -> split out.
// ---------------------------------------------------------------------------
#define LDA 40   // LDS k-stride in ushorts (80B rows; 16B-aligned b128 slots)

template <int EPI>
__device__ __forceinline__ void sgemm_body(
    const unsigned short* __restrict__ Ah, const unsigned short* __restrict__ Al,
    const unsigned short* __restrict__ Bh, const unsigned short* __restrict__ Bl,
    const float* __restrict__ bias, const float* __restrict__ res,
    float* __restrict__ Cf, unsigned short* __restrict__ Ch,
    unsigned short* __restrict__ Cl,
    int M, int N, int K, int m0, int n0,
    unsigned short* sAh, unsigned short* sAl,
    unsigned short* sBh, unsigned short* sBl) {
  int tid = threadIdx.x;
  int lane = tid & 63;
  int w = tid >> 6;
  int wr = w >> 1, wc = w & 1;
  int l15 = lane & 15, l4 = lane >> 4;

  // staging: thread t -> row t>>1 (0..127), k-half (t&1)*16 ; same for A and B^T
  int sr = tid >> 1, skh = (tid & 1) * 16;
  const unsigned short* ApH = Ah + (size_t)(m0 + sr) * K + skh;
  const unsigned short* ApL = Al + (size_t)(m0 + sr) * K + skh;
  const unsigned short* BpH = Bh + (size_t)(n0 + sr) * K + skh;
  const unsigned short* BpL = Bl + (size_t)(n0 + sr) * K + skh;

  u16x8 rah0 = *(const u16x8*)ApH, rah1 = *(const u16x8*)(ApH + 8);
  u16x8 ral0 = *(const u16x8*)ApL, ral1 = *(const u16x8*)(ApL + 8);
  u16x8 rbh0 = *(const u16x8*)BpH, rbh1 = *(const u16x8*)(BpH + 8);
  u16x8 rbl0 = *(const u16x8*)BpL, rbl1 = *(const u16x8*)(BpL + 8);

  f32x4 acc[4][4];
#pragma unroll
  for (int i = 0; i < 4; ++i)
#pragma unroll
    for (int j = 0; j < 4; ++j) acc[i][j] = {0.f, 0.f, 0.f, 0.f};

  int soff = sr * LDA + skh;
  int nsteps = K >> 5;
  for (int s = 0; s < nsteps; ++s) {
    *(u16x8*)&sAh[soff] = rah0; *(u16x8*)&sAh[soff + 8] = rah1;
    *(u16x8*)&sAl[soff] = ral0; *(u16x8*)&sAl[soff + 8] = ral1;
    *(u16x8*)&sBh[soff] = rbh0; *(u16x8*)&sBh[soff + 8] = rbh1;
    *(u16x8*)&sBl[soff] = rbl0; *(u16x8*)&sBl[soff + 8] = rbl1;
    __syncthreads();

    if (s + 1 < nsteps) {       // register prefetch (contiguous along K)
      int ko = (s + 1) * 32;
      rah0 = *(const u16x8*)(ApH + ko); rah1 = *(const u16x8*)(ApH + ko + 8);
      ral0 = *(const u16x8*)(ApL + ko); ral1 = *(const u16x8*)(ApL + ko + 8);
      rbh0 = *(const u16x8*)(BpH + ko); rbh1 = *(const u16x8*)(BpH + ko + 8);
      rbl0 = *(const u16x8*)(BpL + ko); rbl1 = *(const u16x8*)(BpL + ko + 8);
    }

    s16x8 afh[4], afl[4];
    int ab = (wr * 64 + l15) * LDA + 8 * l4;
#pragma unroll
    for (int mr = 0; mr < 4; ++mr) {
      afh[mr] = *(const s16x8*)&sAh[ab + mr * 16 * LDA];
      afl[mr] = *(const s16x8*)&sAl[ab + mr * 16 * LDA];
    }
    int bb = (wc * 64 + l15) * LDA + 8 * l4;
#pragma unroll
    for (int nr = 0; nr < 4; ++nr) {
      s16x8 bfh = *(const s16x8*)&sBh[bb + nr * 16 * LDA];
      s16x8 bfl = *(const s16x8*)&sBl[bb + nr * 16 * LDA];
#pragma unroll
      for (int mr = 0; mr < 4; ++mr) {
        acc[mr][nr] = __builtin_amdgcn_mfma_f32_16x16x32_bf16(afh[mr], bfh, acc[mr][nr], 0, 0, 0);
        acc[mr][nr] = __builtin_amdgcn_mfma_f32_16x16x32_bf16(afl[mr], bfh, acc[mr][nr], 0, 0, 0);
        acc[mr][nr] = __builtin_amdgcn_mfma_f32_16x16x32_bf16(afh[mr], bfl, acc[mr][nr], 0, 0, 0);
      }
    }
    __syncthreads();
  }

  // epilogue: C/D layout col=lane&15, row=(lane>>4)*4+reg  [m89-verified]
  int row0 = m0 + wr * 64 + l4 * 4;
  int col0 = n0 + wc * 64 + l15;
#pragma unroll
  for (int nr = 0; nr < 4; ++nr) {
    int col = col0 + nr * 16;
    float bv = bias[col];
#pragma unroll
    for (int mr = 0; mr < 4; ++mr) {
#pragma unroll
      for (int r = 0; r < 4; ++r) {
        int row = row0 + mr * 16 + r;
        size_t idx = (size_t)row * N + col;
        float v = acc[mr][nr][r] + bv;
        if (EPI == 0) Cf[idx] = v;
        if (EPI == 1) Cf[idx] = v + res[idx];
        if (EPI == 2) {
          float g = gelu_f(v);
          unsigned short hbits = f2bf(g);
          Ch[idx] = hbits;
          Cl[idx] = f2bf(g - bf2f(hbits));
        }
      }
    }
  }
}

template <int EPI>
__global__ __launch_bounds__(256) void sgemm_k(
    const unsigned short* Ah, const unsigned short* Al,
    const unsigned short* Bh, const unsigned short* Bl,
    const float* bias, const float* res,
    float* Cf, unsigned short* Ch, unsigned short* Cl,
    int M, int N, int K) {
  __shared__ unsigned short sAh[128 * LDA];
  __shared__ unsigned short sAl[128 * LDA];
  __shared__ unsigned short sBh[128 * LDA];
  __shared__ unsigned short sBl[128 * LDA];
  sgemm_body<EPI>(Ah, Al, Bh, Bl, bias, res, Cf, Ch, Cl, M, N, K,
                  blockIdx.y * 128, blockIdx.x * 128, sAh, sAl, sBh, sBl);
}

// Fused QKV on the split path: grid.x = 24, blockIdx.x>>3 selects weight.
__global__ __launch_bounds__(256) void sqkv_k(
    const unsigned short* Ah, const unsigned short* Al,
    const unsigned short* wqh, const unsigned short* wql,
    const unsigned short* wkh, const unsigned short* wkl,
    const unsigned short* wvh, const unsigned short* wvl,
    const float* bq, const float* bk, const float* bv,
    float* qo, float* ko, float* vo) {
  __shared__ unsigned short sAh[128 * LDA];
  __shared__ unsigned short sAl[128 * LDA];
  __shared__ unsigned short sBh[128 * LDA];
  __shared__ unsigned short sBl[128 * LDA];
  int which = blockIdx.x >> 3;
  int n0 = (blockIdx.x & 7) * 128;
  const unsigned short* Bh = (which == 0) ? wqh : (which == 1) ? wkh : wvh;
  const unsigned short* Bl = (which == 0) ? wql : (which == 1) ? wkl : wvl;
  const float* bias = (which == 0) ? bq : (which == 1) ? bk : bv;
  float* C = (which == 0) ? qo : (which == 1) ? ko : vo;
  sgemm_body<0>(Ah, Al, Bh, Bl, bias, nullptr, C, nullptr, nullptr,
                MM, CC, CC, blockIdx.y * 128, n0, sAh, sAl, sBh, sBl);
}

// ---------------------------------------------------------------------------
// fp32 fallback GEMM (verified round 2) for small-workspace case.
// ---------------------------------------------------------------------------
#define BK 16
#define LDT 132

template <int EPI>
__device__ __forceinline__ void gemm_body(const float* __restrict__ A,
                                          const float* __restrict__ Bw,
                                          const float* __restrict__ bias,
                                          const float* __restrict__ res,
                                          float* __restrict__ C,
                                          int M, int N, int K,
                                          int m0, int n0,
                                          float (*As)[LDT], float (*Bs)[LDT]) {
  int tid = threadIdx.x;
  int tx = tid & 15, ty = tid >> 4;
  int ar = tid >> 1;
  int aslot = (tid & 1) * 2;
  int brow = tid >> 4;
  int bslot = (tid & 15) * 2;
  const float* Aptr = A + (size_t)(m0 + ar) * K;
  const float* Bptr = Bw + (size_t)brow * N + n0;
  float4 ra0 = ((const float4*)Aptr)[aslot];
  float4 ra1 = ((const float4*)Aptr)[aslot + 1];
  float4 rb0 = ((const float4*)Bptr)[bslot];
  float4 rb1 = ((const float4*)Bptr)[bslot + 1];
  float acc[2][2][4][4] = {};
  for (int k0 = 0; k0 < K; k0 += BK) {
    int ka = aslot * 4;
    As[ka + 0][ar] = ra0.x; As[ka + 1][ar] = ra0.y;
    As[ka + 2][ar] = ra0.z; As[ka + 3][ar] = ra0.w;
    As[ka + 4][ar] = ra1.x; As[ka + 5][ar] = ra1.y;
    As[ka + 6][ar] = ra1.z; As[ka + 7][ar] = ra1.w;
    *(float4*)&Bs[brow][bslot * 4] = rb0;
    *(float4*)&Bs[brow][bslot * 4 + 4] = rb1;
    __syncthreads();
    if (k0 + BK < K) {
      const float* An = Aptr + k0 + BK;
      ra0 = ((const float4*)An)[aslot];
      ra1 = ((const float4*)An)[aslot + 1];
      const float* Bn = Bptr + (size_t)(k0 + BK) * N;
      rb0 = ((const float4*)Bn)[bslot];
      rb1 = ((const float4*)Bn)[bslot + 1];
    }
#pragma unroll
    for (int kk = 0; kk < BK; ++kk) {
      float4 av0 = *(const float4*)&As[kk][ty * 4];
      float4 av1 = *(const float4*)&As[kk][ty * 4 + 64];
      float4 bv0 = *(const float4*)&Bs[kk][tx * 4];
      float4 bv1 = *(const float4*)&Bs[kk][tx * 4 + 64];
      float aa[2][4] = {{av0.x, av0.y, av0.z, av0.w},
                        {av1.x, av1.y, av1.z, av1.w}};
      float bb[2][4] = {{bv0.x, bv0.y, bv0.z, bv0.w},
                        {bv1.x, bv1.y, bv1.z, bv1.w}};
#pragma unroll
      for (int p = 0; p < 2; ++p)
#pragma unroll
        for (int i = 0; i < 4; ++i)
#pragma unroll
          for (int q = 0; q < 2; ++q)
#pragma unroll
            for (int j = 0; j < 4; ++j)
              acc[p][q][i][j] = fmaf(aa[p][i], bb[q][j], acc[p][q][i][j]);
    }
    __syncthreads();
  }
#pragma unroll
  for (int p = 0; p < 2; ++p) {
#pragma unroll
    for (int i = 0; i < 4; ++i) {
      size_t gr = (size_t)(m0 + p * 64 + ty * 4 + i);
      float* Crow = C + gr * N + n0;
#pragma unroll
      for (int q = 0; q < 2; ++q) {
        int c = q * 64 + tx * 4;
        float4 bvv = *(const float4*)&bias[n0 + c];
        float4 o;
        o.x = acc[p][q][i][0] + bvv.x;
        o.y = acc[p][q][i][1] + bvv.y;
        o.z = acc[p][q][i][2] + bvv.z;
        o.w = acc[p][q][i][3] + bvv.w;
        if (EPI == 2) {
          o.x = gelu_f(o.x); o.y = gelu_f(o.y);
          o.z = gelu_f(o.z); o.w = gelu_f(o.w);
        }
        if (EPI == 1) {
          const float* Rrow = res + gr * N + n0;
          float4 rv = *(const float4*)&Rrow[c];
          o.x += rv.x; o.y += rv.y; o.z += rv.z; o.w += rv.w;
        }
        *(float4*)&Crow[c] = o;
      }
    }
  }
}

template <int EPI>
__global__ __launch_bounds__(256) void gemm_k(const float* __restrict__ A,
                                              const float* __restrict__ Bw,
                                              const float* __restrict__ bias,
                                              const float* __restrict__ res,
                                              float* __restrict__ C,
                                              int M, int N, int K) {
  __shared__ float As[BK][LDT];
  __shared__ float Bs[BK][LDT];
  gemm_body<EPI>(A, Bw, bias, res, C, M, N, K,
                 blockIdx.y * 128, blockIdx.x * 128, As, Bs);
}

__global__ __launch_bounds__(256) void qkv_k(const float* __restrict__ A,
                                             const float* __restrict__ wq,
                                             const float* __restrict__ wk,
                                             const float* __restrict__ wv,
                                             const float* __restrict__ bq,
                                             const float* __restrict__ bk,
                                             const float* __restrict__ bv,
                                             float* __restrict__ qo,
                                             float* __restrict__ ko,
                                             float* __restrict__ vo) {
  __shared__ float As[BK][LDT];
  __shared__ float Bs[BK][LDT];
  int which = blockIdx.x >> 3;
  int n0 = (blockIdx.x & 7) * 128;
  const float* Bw = (which == 0) ? wq : (which == 1) ? wk : wv;
  const float* bias = (which == 0) ? bq : (which == 1) ? bk : bv;
  float* C = (which == 0) ? qo : (which == 1) ? ko : vo;
  gemm_body<0>(A, Bw, bias, nullptr, C, MM, CC, CC, blockIdx.y * 128, n0, As, Bs);
}

// ---------------------------------------------------------------------------
// Fused masked attention (fp32 math). OUT=0: fp32 y. OUT=1: split hi/lo y.
// Analytic mask (verified r2): keep = j<=i || (i<1023 && i/10==j/10 && j%10<=8).
// ---------------------------------------------------------------------------
template <int OUT>
__global__ __launch_bounds__(256) void attn_k(const float* __restrict__ q,
                                              const float* __restrict__ k,
                                              const float* __restrict__ v,
                                              float* __restrict__ yf,
                                              unsigned short* __restrict__ yh,
                                              unsigned short* __restrict__ yl) {
  __shared__ float Qs[64][65];
  __shared__ float KPs[64][65];
  __shared__ float Vs[64][64];

  int tid = threadIdx.x;
  int tx = tid & 15, ty = tid >> 4;
  int qb = blockIdx.x;
  int bh = blockIdx.y;
  int b = bh >> 4;
  int h = bh & 15;
  int q0 = qb * 64;

  const float* qbase = q + (size_t)b * TT * CC + (size_t)h * DHH;
  const float* kbase = k + (size_t)b * TT * CC + (size_t)h * DHH;
  const float* vbase = v + (size_t)b * TT * CC + (size_t)h * DHH;

#pragma unroll
  for (int i = 0; i < 4; ++i) {
    int r = ty + 16 * i;
    float4 t = *(const float4*)(qbase + (size_t)(q0 + r) * CC + tx * 4);
    Qs[r][tx * 4 + 0] = t.x; Qs[r][tx * 4 + 1] = t.y;
    Qs[r][tx * 4 + 2] = t.z; Qs[r][tx * 4 + 3] = t.w;
  }

  float mrun[4], lrun[4], accO[4][4];
#pragma unroll
  for (int i = 0; i < 4; ++i) {
    mrun[i] = -1e30f; lrun[i] = 0.0f;
#pragma unroll
    for (int j = 0; j < 4; ++j) accO[i][j] = 0.0f;
  }

  int kbmax = qb + 1; if (kbmax > (TT / 64 - 1)) kbmax = TT / 64 - 1;
  for (int kb = 0; kb <= kbmax; ++kb) {
    int k0 = kb * 64;
    __syncthreads();
#pragma unroll
    for (int i = 0; i < 4; ++i) {
      int r = ty + 16 * i;
      float4 tk = *(const float4*)(kbase + (size_t)(k0 + r) * CC + tx * 4);
      KPs[r][tx * 4 + 0] = tk.x; KPs[r][tx * 4 + 1] = tk.y;
      KPs[r][tx * 4 + 2] = tk.z; KPs[r][tx * 4 + 3] = tk.w;
      float4 tv = *(const float4*)(vbase + (size_t)(k0 + r) * CC + tx * 4);
      *(float4*)&Vs[r][tx * 4] = tv;
    }
    __syncthreads();

    float s[4][4] = {};
    for (int d = 0; d < 64; ++d) {
      float qv[4], kv[4];
#pragma unroll
      for (int i = 0; i < 4; ++i) qv[i] = Qs[ty * 4 + i][d];
#pragma unroll
      for (int j = 0; j < 4; ++j) kv[j] = KPs[tx * 4 + j][d];
#pragma unroll
      for (int i = 0; i < 4; ++i)
#pragma unroll
        for (int j = 0; j < 4; ++j)
          s[i][j] = fmaf(qv[i], kv[j], s[i][j]);
    }
#pragma unroll
    for (int i = 0; i < 4; ++i) {
      int gi = q0 + ty * 4 + i;
#pragma unroll
      for (int j = 0; j < 4; ++j) {
        int gj = k0 + tx * 4 + j;
        bool keep = (gj <= gi) ||
                    ((gi < TT - 1) && (gi / 10 == gj / 10) && (gj % 10 <= 8));
        s[i][j] = keep ? s[i][j] * 0.125f : -1e30f;
      }
    }
    __syncthreads();

#pragma unroll
    for (int i = 0; i < 4; ++i) {
      float mloc = fmaxf(fmaxf(s[i][0], s[i][1]), fmaxf(s[i][2], s[i][3]));
#pragma unroll
      for (int m = 1; m < 16; m <<= 1) mloc = fmaxf(mloc, __shfl_xor(mloc, m, 64));
      float mnew = fmaxf(mrun[i], mloc);
      float p0 = __expf(s[i][0] - mnew);
      float p1 = __expf(s[i][1] - mnew);
      float p2 = __expf(s[i][2] - mnew);
      float p3 = __expf(s[i][3] - mnew);
      float psum = p0 + p1 + p2 + p3;
#pragma unroll
      for (int m = 1; m < 16; m <<= 1) psum += __shfl_xor(psum, m, 64);
      float alpha = __expf(mrun[i] - mnew);
      lrun[i] = lrun[i] * alpha + psum;
      mrun[i] = mnew;
#pragma unroll
      for (int j = 0; j < 4; ++j) accO[i][j] *= alpha;
      KPs[ty * 4 + i][tx * 4 + 0] = p0;
      KPs[ty * 4 + i][tx * 4 + 1] = p1;
      KPs[ty * 4 + i][tx * 4 + 2] = p2;
      KPs[ty * 4 + i][tx * 4 + 3] = p3;
    }
    __syncthreads();

    for (int c = 0; c < 64; ++c) {
      float pr[4];
#pragma unroll
      for (int i = 0; i < 4; ++i) pr[i] = KPs[ty * 4 + i][c];
      float4 vv = *(const float4*)&Vs[c][tx * 4];
      float vb4[4] = {vv.x, vv.y, vv.z, vv.w};
#pragma unroll
      for (int i = 0; i < 4; ++i)
#pragma unroll
        for (int j = 0; j < 4; ++j)
          accO[i][j] = fmaf(pr[i], vb4[j], accO[i][j]);
    }
  }

#pragma unroll
  for (int i = 0; i < 4; ++i) {
    float inv = 1.0f / lrun[i];
    size_t row = (size_t)(b * TT + q0 + ty * 4 + i);
    int col = h * DHH + tx * 4;
    if (OUT == 0) {
      float4 o;
      o.x = accO[i][0] * inv; o.y = accO[i][1] * inv;
      o.z = accO[i][2] * inv; o.w = accO[i][3] * inv;
      *(float4*)(yf + row * CC + col) = o;
    } else {
      u16x4 hb, lb;
#pragma unroll
      for (int j = 0; j < 4; ++j) {
        float g = accO[i][j] * inv;
        hb[j] = f2bf(g);
        lb[j] = f2bf(g - bf2f(hb[j]));
      }
      *(u16x4*)(yh + row * CC + col) = hb;
      *(u16x4*)(yl + row * CC + col) = lb;
    }
  }
}

// ---------------------------------------------------------------------------
extern "C" void kernel_launch(void* const* d_in, const int* in_sizes, int n_in,
                              void* d_out, int out_size, void* d_ws, size_t ws_size,
                              hipStream_t stream) {
  (void)in_sizes; (void)n_in; (void)out_size;
  const float* x    = (const float*)d_in[0];
  const float* ln1w = (const float*)d_in[1];
  const float* ln1b = (const float*)d_in[2];
  const float* ln2w = (const float*)d_in[3];
  const float* ln2b = (const float*)d_in[4];
  const float* wq   = (const float*)d_in[5];
  const float* bq   = (const float*)d_in[6];
  const float* wk   = (const float*)d_in[7];
  const float* bk   = (const float*)d_in[8];
  const float* wv   = (const float*)d_in[9];
  const float* bv   = (const float*)d_in[10];
  const float* wo   = (const float*)d_in[11];
  const float* bo   = (const float*)d_in[12];
  const float* w1   = (const float*)d_in[13];
  const float* b1   = (const float*)d_in[14];
  const float* w2   = (const float*)d_in[15];
  const float* b2   = (const float*)d_in[16];
  float* out = (float*)d_out;

  const size_t SZ = (size_t)MM * CC;  // 4M elements
  hipMemcpyAsync(out, x, SZ * sizeof(float), hipMemcpyDeviceToDevice, stream);

  const size_t MB = 1024 * 1024;
  if (ws_size >= 112 * MB) {
    // ------------------- split-bf16 MFMA path -------------------
    unsigned short* u = (unsigned short*)d_ws;
    const size_t Mu = 1024 * 1024;
    unsigned short* wqh = u;            unsigned short* wql = u + 1 * Mu;
    unsigned short* wkh = u + 2 * Mu;   unsigned short* wkl = u + 3 * Mu;
    unsigned short* wvh = u + 4 * Mu;   unsigned short* wvl = u + 5 * Mu;
    unsigned short* woh = u + 6 * Mu;   unsigned short* wol = u + 7 * Mu;
    unsigned short* w1h = u + 8 * Mu;   unsigned short* w1l = u + 12 * Mu;
    unsigned short* w2h = u + 16 * Mu;  unsigned short* w2l = u + 20 * Mu;
    unsigned short* hh  = u + 24 * Mu;  unsigned short* hl  = u + 28 * Mu;
    float* qf = (float*)(u + 32 * Mu);
    float* kf = qf + 4 * Mu;
    float* vf = kf + 4 * Mu;
    unsigned short* hidh;
    unsigned short* hidl;
    int nch;
    if (ws_size >= 176 * MB) {
      hidh = (unsigned short*)(vf + 4 * Mu);
      hidl = hidh + 16 * Mu;
      nch = 1;
    } else {
      hidh = (unsigned short*)qf;   // q/k dead during MLP; chunked reuse
      hidl = hidh + 8 * Mu;
      nch = 2;
    }
    int mch = MM / nch;

    for (int l = 0; l < LL; ++l) {
      SplitArgs sa;
      sa.src[0] = wq + (size_t)l * CC * CC;  sa.dh[0] = wqh; sa.dl[0] = wql;
      sa.src[1] = wk + (size_t)l * CC * CC;  sa.dh[1] = wkh; sa.dl[1] = wkl;
      sa.src[2] = wv + (size_t)l * CC * CC;  sa.dh[2] = wvh; sa.dl[2] = wvl;
      sa.src[3] = wo + (size_t)l * CC * CC;  sa.dh[3] = woh; sa.dl[3] = wol;
      sa.src[4] = w1 + (size_t)l * CC * FFF; sa.dh[4] = w1h; sa.dl[4] = w1l;
      sa.src[5] = w2 + (size_t)l * FFF * CC; sa.dh[5] = w2h; sa.dl[5] = w2l;
      splitT_k<<<3072, 256, 0, stream>>>(sa);

      ln_k<1><<<MM, 256, 0, stream>>>(out, ln1w + (size_t)l * CC, ln1b + (size_t)l * CC,
                                      nullptr, hh, hl);
      sqkv_k<<<dim3(24, MM / 128), 256, 0, stream>>>(
          hh, hl, wqh, wql, wkh, wkl, wvh, wvl,
          bq + (size_t)l * CC, bk + (size_t)l * CC, bv + (size_t)l * CC,
          qf, kf, vf);
      attn_k<1><<<dim3(TT / 64, BB * HH), 256, 0, stream>>>(qf, kf, vf, nullptr, hh, hl);
      sgemm_k<1><<<dim3(CC / 128, MM / 128), 256, 0, stream>>>(
          hh, hl, woh, wol, bo + (size_t)l * CC, out, out, nullptr, nullptr, MM, CC, CC);
      ln_k<1><<<MM, 256, 0, stream>>>(out, ln2w + (size_t)l * CC, ln2b + (size_t)l * CC,
                                      nullptr, hh, hl);
      for (int c = 0; c < nch; ++c) {
        size_t aoff = (size_t)c * mch * CC;
        sgemm_k<2><<<dim3(FFF / 128, mch / 128), 256, 0, stream>>>(
            hh + aoff, hl + aoff, w1h, w1l, b1 + (size_t)l * FFF, nullptr,
            nullptr, hidh, hidl, mch, FFF, CC);
        sgemm_k<1><<<dim3(CC / 128, mch / 128), 256, 0, stream>>>(
            hidh, hidl, w2h, w2l, b2 + (size_t)l * CC, out + aoff,
            out + aoff, nullptr, nullptr, mch, CC, FFF);
      }
    }
  } else {
    // ------------------- fp32 fallback path (verified round 2) ------------
    float* hbuf = (float*)d_ws;
    float* qbuf = hbuf + SZ;
    float* kbuf = qbuf + SZ;
    float* vbuf = kbuf + SZ;
    float* hid;
    int nch;
    if (ws_size >= (4 * SZ + (size_t)MM * FFF) * sizeof(float)) {
      hid = vbuf + SZ; nch = 1;
    } else {
      hid = qbuf; nch = 2;
    }
    int mch = MM / nch;
    dim3 gProj(CC / 128, MM / 128);
    for (int l = 0; l < LL; ++l) {
      const float* wq_l = wq + (size_t)l * CC * CC;
      const float* wk_l = wk + (size_t)l * CC * CC;
      const float* wv_l = wv + (size_t)l * CC * CC;
      const float* wo_l = wo + (size_t)l * CC * CC;
      const float* w1_l = w1 + (size_t)l * CC * FFF;
      const float* w2_l = w2 + (size_t)l * FFF * CC;
      ln_k<0><<<MM, 256, 0, stream>>>(out, ln1w + (size_t)l * CC, ln1b + (size_t)l * CC,
                                      hbuf, nullptr, nullptr);
      qkv_k<<<dim3(24, MM / 128), 256, 0, stream>>>(
          hbuf, wq_l, wk_l, wv_l,
          bq + (size_t)l * CC, bk + (size_t)l * CC, bv + (size_t)l * CC,
          qbuf, kbuf, vbuf);
      attn_k<0><<<dim3(TT / 64, BB * HH), 256, 0, stream>>>(qbuf, kbuf, vbuf,
                                                            hbuf, nullptr, nullptr);
      gemm_k<1><<<gProj, 256, 0, stream>>>(hbuf, wo_l, bo + (size_t)l * CC, out, out, MM, CC, CC);
      ln_k<0><<<MM, 256, 0, stream>>>(out, ln2w + (size_t)l * CC, ln2b + (size_t)l * CC,
                                      hbuf, nullptr, nullptr);
      for (int c = 0; c < nch; ++c) {
        const float* aoff = hbuf + (size_t)c * mch * CC;
        float* ooff = out + (size_t)c * mch * CC;
        gemm_k<2><<<dim3(FFF / 128, mch / 128), 256, 0, stream>>>(
            aoff, w1_l, b1 + (size_t)l * FFF, nullptr, hid, mch, FFF, CC);
        gemm_k<1><<<dim3(CC / 128, mch / 128), 256, 0, stream>>>(
            hid, w2_l, b2 + (size_t)l * CC, ooff, ooff, mch, CC, FFF);
      }
    }
  }
}

// Round 5
// 5877.026 us; speedup vs baseline: 2.1765x; 1.0216x over previous
//
#include <hip/hip_runtime.h>

#define TT 1024
#define CC 1024
#define HH 16
#define DHH 64
#define BB 4
#define LL 8
#define FFF 4096
#define MM (BB*TT)   // 4096 rows

typedef float f32x4 __attribute__((ext_vector_type(4)));
typedef short s16x8 __attribute__((ext_vector_type(8)));
typedef unsigned short u16x8 __attribute__((ext_vector_type(8)));
typedef unsigned short u16x4 __attribute__((ext_vector_type(4)));

__device__ __forceinline__ unsigned short f2bf(float x) {
  unsigned int u = __float_as_uint(x);
  unsigned int r = u + 0x7FFFu + ((u >> 16) & 1u);   // RNE
  return (unsigned short)(r >> 16);
}
__device__ __forceinline__ float bf2f(unsigned short h) {
  return __uint_as_float(((unsigned int)h) << 16);
}
__device__ __forceinline__ float gelu_f(float x) {
  return 0.5f * x * (1.0f + erff(x * 0.70710678118654752f));
}

// ---------------------------------------------------------------------------
// Weight split+TRANSPOSE kernel: W[K][N] fp32 -> Wt_hi/Wt_lo[N][K] bf16 bits.
// ---------------------------------------------------------------------------
struct SplitArgs {
  const float* src[6];
  unsigned short* dh[6];
  unsigned short* dl[6];
};

__global__ __launch_bounds__(256) void splitT_k(SplitArgs a) {
  __shared__ float Ls[64][65];
  int idx = blockIdx.x;
  int r, t;
  if (idx < 1024)      { r = idx >> 8; t = idx & 255; }
  else if (idx < 2048) { r = 4; t = idx - 1024; }
  else                 { r = 5; t = idx - 2048; }
  int K = (r == 5) ? FFF : CC;
  int N = (r == 4) ? FFF : CC;
  int Nt = N >> 6;
  int k0 = (t / Nt) * 64, n0 = (t % Nt) * 64;

  const float* s = a.src[r];
  int tid = threadIdx.x;
  int rrow = tid >> 4, rcol = tid & 15;
#pragma unroll
  for (int i = 0; i < 4; ++i) {
    int rl = rrow + 16 * i;
    float4 v = *(const float4*)(s + (size_t)(k0 + rl) * N + n0 + rcol * 4);
    Ls[rl][rcol * 4 + 0] = v.x; Ls[rl][rcol * 4 + 1] = v.y;
    Ls[rl][rcol * 4 + 2] = v.z; Ls[rl][rcol * 4 + 3] = v.w;
  }
  __syncthreads();

  int nl = tid >> 2, ks = (tid & 3) * 16;
  u16x8 h0, h1, l0, l1;
#pragma unroll
  for (int j = 0; j < 8; ++j) {
    float f = Ls[ks + j][nl];
    h0[j] = f2bf(f); l0[j] = f2bf(f - bf2f(h0[j]));
  }
#pragma unroll
  for (int j = 0; j < 8; ++j) {
    float f = Ls[ks + 8 + j][nl];
    h1[j] = f2bf(f); l1[j] = f2bf(f - bf2f(h1[j]));
  }
  size_t o = (size_t)(n0 + nl) * K + k0 + ks;
  *(u16x8*)(a.dh[r] + o) = h0; *(u16x8*)(a.dh[r] + o + 8) = h1;
  *(u16x8*)(a.dl[r] + o) = l0; *(u16x8*)(a.dl[r] + o + 8) = l1;
}

// ---------------------------------------------------------------------------
// LayerNorm. OUT=0: fp32 out. OUT=1: split bf16 hi/lo out.
// ---------------------------------------------------------------------------
template <int OUT>
__global__ __launch_bounds__(256) void ln_k(const float* __restrict__ x,
                                            const float* __restrict__ w,
                                            const float* __restrict__ b,
                                            float* __restrict__ of,
                                            unsigned short* __restrict__ oh,
                                            unsigned short* __restrict__ ol) {
  int row = blockIdx.x;
  int tid = threadIdx.x;
  const float* xr = x + (size_t)row * CC;
  float4 v = ((const float4*)xr)[tid];
  float s = v.x + v.y + v.z + v.w;
#pragma unroll
  for (int m = 1; m < 64; m <<= 1) s += __shfl_xor(s, m, 64);
  __shared__ float r1[4];
  __shared__ float r2[4];
  if ((tid & 63) == 0) r1[tid >> 6] = s;
  __syncthreads();
  float mu = (r1[0] + r1[1] + r1[2] + r1[3]) * (1.0f / CC);
  float d0 = v.x - mu, d1 = v.y - mu, d2 = v.z - mu, d3 = v.w - mu;
  float sq = d0 * d0 + d1 * d1 + d2 * d2 + d3 * d3;
#pragma unroll
  for (int m = 1; m < 64; m <<= 1) sq += __shfl_xor(sq, m, 64);
  if ((tid & 63) == 0) r2[tid >> 6] = sq;
  __syncthreads();
  float var = (r2[0] + r2[1] + r2[2] + r2[3]) * (1.0f / CC);
  float rs = rsqrtf(var + 1e-5f);
  float4 wv = ((const float4*)w)[tid];
  float4 bv = ((const float4*)b)[tid];
  float o0 = d0 * rs * wv.x + bv.x;
  float o1 = d1 * rs * wv.y + bv.y;
  float o2 = d2 * rs * wv.z + bv.z;
  float o3 = d3 * rs * wv.w + bv.w;
  if (OUT == 0) {
    float4 ov; ov.x = o0; ov.y = o1; ov.z = o2; ov.w = o3;
    ((float4*)(of + (size_t)row * CC))[tid] = ov;
  } else {
    u16x4 h, lo;
    h[0] = f2bf(o0); lo[0] = f2bf(o0 - bf2f(h[0]));
    h[1] = f2bf(o1); lo[1] = f2bf(o1 - bf2f(h[1]));
    h[2] = f2bf(o2); lo[2] = f2bf(o2 - bf2f(h[2]));
    h[3] = f2bf(o3); lo[3] = f2bf(o3 - bf2f(h[3]));
    *(u16x4*)(oh + (size_t)row * CC + tid * 4) = h;
    *(u16x4*)(ol + (size_t)row * CC + tid * 4) = lo;
  }
}

// ---------------------------------------------------------------------------
// Split-bf16 MFMA GEMM. Both operands [row][K] (weights pre-transposed).
// EPI: 0=+bias fp32; 1=+bias+res fp32; 2=gelu->split; 3=split; 4=split*0.125;
//      5=split transposed (V: [bh*64+dv][t]).
// ---------------------------------------------------------------------------
#define LDA 40   // LDS k-stride in ushorts

template <int EPI>
__device__ __forceinline__ void sgemm_body(
    const unsigned short* __restrict__ Ah, const unsigned short* __restrict__ Al,
    const unsigned short* __restrict__ Bh, const unsigned short* __restrict__ Bl,
    const float* __restrict__ bias, const float* __restrict__ res,
    float* __restrict__ Cf, unsigned short* __restrict__ Ch,
    unsigned short* __restrict__ Cl,
    int M, int N, int K, int m0, int n0,
    unsigned short* sAh, unsigned short* sAl,
    unsigned short* sBh, unsigned short* sBl) {
  int tid = threadIdx.x;
  int lane = tid & 63;
  int w = tid >> 6;
  int wr = w >> 1, wc = w & 1;
  int l15 = lane & 15, l4 = lane >> 4;

  int sr = tid >> 1, skh = (tid & 1) * 16;
  const unsigned short* ApH = Ah + (size_t)(m0 + sr) * K + skh;
  const unsigned short* ApL = Al + (size_t)(m0 + sr) * K + skh;
  const unsigned short* BpH = Bh + (size_t)(n0 + sr) * K + skh;
  const unsigned short* BpL = Bl + (size_t)(n0 + sr) * K + skh;

  u16x8 rah0 = *(const u16x8*)ApH, rah1 = *(const u16x8*)(ApH + 8);
  u16x8 ral0 = *(const u16x8*)ApL, ral1 = *(const u16x8*)(ApL + 8);
  u16x8 rbh0 = *(const u16x8*)BpH, rbh1 = *(const u16x8*)(BpH + 8);
  u16x8 rbl0 = *(const u16x8*)BpL, rbl1 = *(const u16x8*)(BpL + 8);

  f32x4 acc[4][4];
#pragma unroll
  for (int i = 0; i < 4; ++i)
#pragma unroll
    for (int j = 0; j < 4; ++j) acc[i][j] = {0.f, 0.f, 0.f, 0.f};

  int soff = sr * LDA + skh;
  int nsteps = K >> 5;
  for (int s = 0; s < nsteps; ++s) {
    *(u16x8*)&sAh[soff] = rah0; *(u16x8*)&sAh[soff + 8] = rah1;
    *(u16x8*)&sAl[soff] = ral0; *(u16x8*)&sAl[soff + 8] = ral1;
    *(u16x8*)&sBh[soff] = rbh0; *(u16x8*)&sBh[soff + 8] = rbh1;
    *(u16x8*)&sBl[soff] = rbl0; *(u16x8*)&sBl[soff + 8] = rbl1;
    __syncthreads();

    if (s + 1 < nsteps) {
      int ko = (s + 1) * 32;
      rah0 = *(const u16x8*)(ApH + ko); rah1 = *(const u16x8*)(ApH + ko + 8);
      ral0 = *(const u16x8*)(ApL + ko); ral1 = *(const u16x8*)(ApL + ko + 8);
      rbh0 = *(const u16x8*)(BpH + ko); rbh1 = *(const u16x8*)(BpH + ko + 8);
      rbl0 = *(const u16x8*)(BpL + ko); rbl1 = *(const u16x8*)(BpL + ko + 8);
    }

    s16x8 afh[4], afl[4];
    int ab = (wr * 64 + l15) * LDA + 8 * l4;
#pragma unroll
    for (int mr = 0; mr < 4; ++mr) {
      afh[mr] = *(const s16x8*)&sAh[ab + mr * 16 * LDA];
      afl[mr] = *(const s16x8*)&sAl[ab + mr * 16 * LDA];
    }
    int bb = (wc * 64 + l15) * LDA + 8 * l4;
#pragma unroll
    for (int nr = 0; nr < 4; ++nr) {
      s16x8 bfh = *(const s16x8*)&sBh[bb + nr * 16 * LDA];
      s16x8 bfl = *(const s16x8*)&sBl[bb + nr * 16 * LDA];
#pragma unroll
      for (int mr = 0; mr < 4; ++mr) {
        acc[mr][nr] = __builtin_amdgcn_mfma_f32_16x16x32_bf16(afh[mr], bfh, acc[mr][nr], 0, 0, 0);
        acc[mr][nr] = __builtin_amdgcn_mfma_f32_16x16x32_bf16(afl[mr], bfh, acc[mr][nr], 0, 0, 0);
        acc[mr][nr] = __builtin_amdgcn_mfma_f32_16x16x32_bf16(afh[mr], bfl, acc[mr][nr], 0, 0, 0);
      }
    }
    __syncthreads();
  }

  // epilogue: C/D layout col=lane&15, row=(lane>>4)*4+reg  [m89-verified]
  int row0 = m0 + wr * 64 + l4 * 4;
  int col0 = n0 + wc * 64 + l15;
  if (EPI == 5) {
#pragma unroll
    for (int nr = 0; nr < 4; ++nr) {
      int col = col0 + nr * 16;
      float bv = bias[col];
#pragma unroll
      for (int mr = 0; mr < 4; ++mr) {
        int row = row0 + mr * 16;           // 4 consecutive token rows
        int t0 = row & (TT - 1);
        size_t vrow = (size_t)((row >> 10) << 10) + col;  // (b*16+h)*64+dv
        u16x4 hb, lb;
#pragma unroll
        for (int r = 0; r < 4; ++r) {
          float v = acc[mr][nr][r] + bv;
          hb[r] = f2bf(v); lb[r] = f2bf(v - bf2f(hb[r]));
        }
        *(u16x4*)(Ch + vrow * TT + t0) = hb;
        *(u16x4*)(Cl + vrow * TT + t0) = lb;
      }
    }
    return;
  }
#pragma unroll
  for (int nr = 0; nr < 4; ++nr) {
    int col = col0 + nr * 16;
    float bv = bias[col];
#pragma unroll
    for (int mr = 0; mr < 4; ++mr) {
#pragma unroll
      for (int r = 0; r < 4; ++r) {
        int row = row0 + mr * 16 + r;
        size_t idx = (size_t)row * N + col;
        float v = acc[mr][nr][r] + bv;
        if (EPI == 0) Cf[idx] = v;
        if (EPI == 1) Cf[idx] = v + res[idx];
        if (EPI == 2 || EPI == 3 || EPI == 4) {
          float g = (EPI == 2) ? gelu_f(v) : (EPI == 4) ? v * 0.125f : v;
          unsigned short hbits = f2bf(g);
          Ch[idx] = hbits;
          Cl[idx] = f2bf(g - bf2f(hbits));
        }
      }
    }
  }
}

template <int EPI>
__global__ __launch_bounds__(256) void sgemm_k(
    const unsigned short* Ah, const unsigned short* Al,
    const unsigned short* Bh, const unsigned short* Bl,
    const float* bias, const float* res,
    float* Cf, unsigned short* Ch, unsigned short* Cl,
    int M, int N, int K) {
  __shared__ unsigned short sAh[128 * LDA];
  __shared__ unsigned short sAl[128 * LDA];
  __shared__ unsigned short sBh[128 * LDA];
  __shared__ unsigned short sBl[128 * LDA];
  sgemm_body<EPI>(Ah, Al, Bh, Bl, bias, res, Cf, Ch, Cl, M, N, K,
                  blockIdx.y * 128, blockIdx.x * 128, sAh, sAl, sBh, sBl);
}

// Fused QKV producing split bf16 outputs directly:
// Q (scaled 0.125) token-major; K token-major; V transposed [bh*64+dv][t].
__global__ __launch_bounds__(256) void sqkv_k(
    const unsigned short* Ah, const unsigned short* Al,
    const unsigned short* wqh, const unsigned short* wql,
    const unsigned short* wkh, const unsigned short* wkl,
    const unsigned short* wvh, const unsigned short* wvl,
    const float* bq, const float* bk, const float* bv,
    unsigned short* qhp, unsigned short* qlp,
    unsigned short* khp, unsigned short* klp,
    unsigned short* vth, unsigned short* vtl) {
  __shared__ unsigned short sAh[128 * LDA];
  __shared__ unsigned short sAl[128 * LDA];
  __shared__ unsigned short sBh[128 * LDA];
  __shared__ unsigned short sBl[128 * LDA];
  int which = blockIdx.x >> 3;
  int n0 = (blockIdx.x & 7) * 128;
  int m0 = blockIdx.y * 128;
  if (which == 0) {
    sgemm_body<4>(Ah, Al, wqh, wql, bq, nullptr, nullptr, qhp, qlp,
                  MM, CC, CC, m0, n0, sAh, sAl, sBh, sBl);
  } else if (which == 1) {
    sgemm_body<3>(Ah, Al, wkh, wkl, bk, nullptr, nullptr, khp, klp,
                  MM, CC, CC, m0, n0, sAh, sAl, sBh, sBl);
  } else {
    sgemm_body<5>(Ah, Al, wvh, wvl, bv, nullptr, nullptr, vth, vtl,
                  MM, CC, CC, m0, n0, sAh, sAl, sBh, sBl);
  }
}

// ---------------------------------------------------------------------------
// MFMA flash attention. Block = 64 q-rows of one (b,h); 4 independent waves
// (16 q-rows each), no barriers. Split hi/lo (3 MFMAs) for QK^T and PV.
// Q pre-scaled by 0.125. V in transposed layout [bh*64+dv][t].
// Analytic mask: keep = k<=q || (q<1023 && q/10==k/10 && k%10<=8).
// ---------------------------------------------------------------------------
#define LDP 72   // P LDS row stride (u16); 144B rows keep b128 reads aligned

__global__ __launch_bounds__(256) void mattn_k(
    const unsigned short* __restrict__ qh, const unsigned short* __restrict__ ql,
    const unsigned short* __restrict__ kh, const unsigned short* __restrict__ kl,
    const unsigned short* __restrict__ vth, const unsigned short* __restrict__ vtl,
    unsigned short* __restrict__ yh, unsigned short* __restrict__ yl) {
  __shared__ unsigned short Pbuf[4][2][16 * LDP];

  int tid = threadIdx.x;
  int lane = tid & 63;
  int w = tid >> 6;
  int c = lane & 15, g = lane >> 4;
  int qb = (int)gridDim.x - 1 - blockIdx.x;   // long blocks first
  int bh = blockIdx.y;
  int b = bh >> 4, h = bh & 15;
  int q0w = qb * 64 + w * 16;

  unsigned short* ph = Pbuf[w][0];
  unsigned short* pl = Pbuf[w][1];

  // Q A-fragments (held in regs whole kernel): row=c, d = 8g (+32*step)
  const size_t qoff = (size_t)(b * TT + q0w + c) * CC + h * DHH + 8 * g;
  s16x8 qa00 = *(const s16x8*)(qh + qoff);
  s16x8 qa01 = *(const s16x8*)(ql + qoff);
  s16x8 qa10 = *(const s16x8*)(qh + qoff + 32);
  s16x8 qa11 = *(const s16x8*)(ql + qoff + 32);

  int qq[4], qdiv[4];
#pragma unroll
  for (int r = 0; r < 4; ++r) { qq[r] = q0w + 4 * g + r; qdiv[r] = qq[r] / 10; }

  float mrun[4], lrun[4];
  f32x4 accO[4];
#pragma unroll
  for (int r = 0; r < 4; ++r) { mrun[r] = -1e30f; lrun[r] = 0.f; }
#pragma unroll
  for (int t = 0; t < 4; ++t) accO[t] = {0.f, 0.f, 0.f, 0.f};

  const size_t kbase = (size_t)(b * TT) * CC + h * DHH;
  const size_t vbase = (size_t)((b * HH + h) * DHH) * TT;

  int kbmax = qb + 1; if (kbmax > TT / 64 - 1) kbmax = TT / 64 - 1;
  for (int kb = 0; kb <= kbmax; ++kb) {
    int k0 = kb * 64;
    if (k0 > q0w + 24) continue;   // no keepable element for this wave

    // ---- S = Q K^T (scaled already) ----
    f32x4 st[4];
#pragma unroll
    for (int nt = 0; nt < 4; ++nt) st[nt] = {0.f, 0.f, 0.f, 0.f};
#pragma unroll
    for (int nt = 0; nt < 4; ++nt) {
      size_t ko = kbase + (size_t)(k0 + nt * 16 + c) * CC + 8 * g;
      s16x8 kbh0 = *(const s16x8*)(kh + ko);
      s16x8 kbl0 = *(const s16x8*)(kl + ko);
      s16x8 kbh1 = *(const s16x8*)(kh + ko + 32);
      s16x8 kbl1 = *(const s16x8*)(kl + ko + 32);
      st[nt] = __builtin_amdgcn_mfma_f32_16x16x32_bf16(qa00, kbh0, st[nt], 0, 0, 0);
      st[nt] = __builtin_amdgcn_mfma_f32_16x16x32_bf16(qa01, kbh0, st[nt], 0, 0, 0);
      st[nt] = __builtin_amdgcn_mfma_f32_16x16x32_bf16(qa00, kbl0, st[nt], 0, 0, 0);
      st[nt] = __builtin_amdgcn_mfma_f32_16x16x32_bf16(qa10, kbh1, st[nt], 0, 0, 0);
      st[nt] = __builtin_amdgcn_mfma_f32_16x16x32_bf16(qa11, kbh1, st[nt], 0, 0, 0);
      st[nt] = __builtin_amdgcn_mfma_f32_16x16x32_bf16(qa10, kbl1, st[nt], 0, 0, 0);
    }

    // ---- mask + online softmax (rows lane-local via C-layout) ----
    bool full = (k0 + 63 <= q0w);   // whole tile causal-kept for all wave rows
    float alpha[4];
#pragma unroll
    for (int r = 0; r < 4; ++r) {
      if (!full) {
#pragma unroll
        for (int nt = 0; nt < 4; ++nt) {
          int kk = k0 + nt * 16 + c;
          bool keep = (kk <= qq[r]) ||
                      ((qq[r] < TT - 1) && (qdiv[r] == kk / 10) && (kk % 10 <= 8));
          if (!keep) st[nt][r] = -1e30f;
        }
      }
      float mm = fmaxf(fmaxf(st[0][r], st[1][r]), fmaxf(st[2][r], st[3][r]));
      mm = fmaxf(mm, __shfl_xor(mm, 1));
      mm = fmaxf(mm, __shfl_xor(mm, 2));
      mm = fmaxf(mm, __shfl_xor(mm, 4));
      mm = fmaxf(mm, __shfl_xor(mm, 8));
      float mnew = fmaxf(mrun[r], mm);
      alpha[r] = __expf(mrun[r] - mnew);
      mrun[r] = mnew;
      float ls = 0.f;
#pragma unroll
      for (int nt = 0; nt < 4; ++nt) {
        float p = __expf(st[nt][r] - mnew);
        ls += p;
        unsigned short hi = f2bf(p);
        int po = (4 * g + r) * LDP + nt * 16 + c;
        ph[po] = hi;
        pl[po] = f2bf(p - bf2f(hi));
      }
      ls += __shfl_xor(ls, 1); ls += __shfl_xor(ls, 2);
      ls += __shfl_xor(ls, 4); ls += __shfl_xor(ls, 8);
      lrun[r] = lrun[r] * alpha[r] + ls;
    }
#pragma unroll
    for (int t = 0; t < 4; ++t) {
      accO[t][0] *= alpha[0]; accO[t][1] *= alpha[1];
      accO[t][2] *= alpha[2]; accO[t][3] *= alpha[3];
    }

    // within-wave LDS RAW ordering (cross-lane dep the compiler can't see)
    asm volatile("s_waitcnt lgkmcnt(0)" ::: "memory");

    // ---- O += P V ----
#pragma unroll
    for (int ks = 0; ks < 2; ++ks) {
      s16x8 pah = *(const s16x8*)&ph[c * LDP + 32 * ks + 8 * g];
      s16x8 pal = *(const s16x8*)&pl[c * LDP + 32 * ks + 8 * g];
#pragma unroll
      for (int dvt = 0; dvt < 4; ++dvt) {
        size_t vo = vbase + (size_t)(dvt * 16 + c) * TT + k0 + 32 * ks + 8 * g;
        s16x8 vbh = *(const s16x8*)(vth + vo);
        s16x8 vbl = *(const s16x8*)(vtl + vo);
        accO[dvt] = __builtin_amdgcn_mfma_f32_16x16x32_bf16(pah, vbh, accO[dvt], 0, 0, 0);
        accO[dvt] = __builtin_amdgcn_mfma_f32_16x16x32_bf16(pal, vbh, accO[dvt], 0, 0, 0);
        accO[dvt] = __builtin_amdgcn_mfma_f32_16x16x32_bf16(pah, vbl, accO[dvt], 0, 0, 0);
      }
    }
  }

  // ---- normalize + split output (token-major, feeds wo projection) ----
#pragma unroll
  for (int r = 0; r < 4; ++r) {
    float inv = 1.0f / lrun[r];
    size_t yo = (size_t)(b * TT + qq[r]) * CC + h * DHH;
#pragma unroll
    for (int dvt = 0; dvt < 4; ++dvt) {
      float o = accO[dvt][r] * inv;
      unsigned short hi = f2bf(o);
      yh[yo + dvt * 16 + c] = hi;
      yl[yo + dvt * 16 + c] = f2bf(o - bf2f(hi));
    }
  }
}

// ---------------------------------------------------------------------------
// fp32 fallback GEMM + attention (verified round 2) for small workspace.
// ---------------------------------------------------------------------------
#define BK 16
#define LDT 132

template <int EPI>
__device__ __forceinline__ void gemm_body(const float* __restrict__ A,
                                          const float* __restrict__ Bw,
                                          const float* __restrict__ bias,
                                          const float* __restrict__ res,
                                          float* __restrict__ C,
                                          int M, int N, int K,
                                          int m0, int n0,
                                          float (*As)[LDT], float (*Bs)[LDT]) {
  int tid = threadIdx.x;
  int tx = tid & 15, ty = tid >> 4;
  int ar = tid >> 1;
  int aslot = (tid & 1) * 2;
  int brow = tid >> 4;
  int bslot = (tid & 15) * 2;
  const float* Aptr = A + (size_t)(m0 + ar) * K;
  const float* Bptr = Bw + (size_t)brow * N + n0;
  float4 ra0 = ((const float4*)Aptr)[aslot];
  float4 ra1 = ((const float4*)Aptr)[aslot + 1];
  float4 rb0 = ((const float4*)Bptr)[bslot];
  float4 rb1 = ((const float4*)Bptr)[bslot + 1];
  float acc[2][2][4][4] = {};
  for (int k0 = 0; k0 < K; k0 += BK) {
    int ka = aslot * 4;
    As[ka + 0][ar] = ra0.x; As[ka + 1][ar] = ra0.y;
    As[ka + 2][ar] = ra0.z; As[ka + 3][ar] = ra0.w;
    As[ka + 4][ar] = ra1.x; As[ka + 5][ar] = ra1.y;
    As[ka + 6][ar] = ra1.z; As[ka + 7][ar] = ra1.w;
    *(float4*)&Bs[brow][bslot * 4] = rb0;
    *(float4*)&Bs[brow][bslot * 4 + 4] = rb1;
    __syncthreads();
    if (k0 + BK < K) {
      const float* An = Aptr + k0 + BK;
      ra0 = ((const float4*)An)[aslot];
      ra1 = ((const float4*)An)[aslot + 1];
      const float* Bn = Bptr + (size_t)(k0 + BK) * N;
      rb0 = ((const float4*)Bn)[bslot];
      rb1 = ((const float4*)Bn)[bslot + 1];
    }
#pragma unroll
    for (int kk = 0; kk < BK; ++kk) {
      float4 av0 = *(const float4*)&As[kk][ty * 4];
      float4 av1 = *(const float4*)&As[kk][ty * 4 + 64];
      float4 bv0 = *(const float4*)&Bs[kk][tx * 4];
      float4 bv1 = *(const float4*)&Bs[kk][tx * 4 + 64];
      float aa[2][4] = {{av0.x, av0.y, av0.z, av0.w},
                        {av1.x, av1.y, av1.z, av1.w}};
      float bb[2][4] = {{bv0.x, bv0.y, bv0.z, bv0.w},
                        {bv1.x, bv1.y, bv1.z, bv1.w}};
#pragma unroll
      for (int p = 0; p < 2; ++p)
#pragma unroll
        for (int i = 0; i < 4; ++i)
#pragma unroll
          for (int q = 0; q < 2; ++q)
#pragma unroll
            for (int j = 0; j < 4; ++j)
              acc[p][q][i][j] = fmaf(aa[p][i], bb[q][j], acc[p][q][i][j]);
    }
    __syncthreads();
  }
#pragma unroll
  for (int p = 0; p < 2; ++p) {
#pragma unroll
    for (int i = 0; i < 4; ++i) {
      size_t gr = (size_t)(m0 + p * 64 + ty * 4 + i);
      float* Crow = C + gr * N + n0;
#pragma unroll
      for (int q = 0; q < 2; ++q) {
        int cidx = q * 64 + tx * 4;
        float4 bvv = *(const float4*)&bias[n0 + cidx];
        float4 o;
        o.x = acc[p][q][i][0] + bvv.x;
        o.y = acc[p][q][i][1] + bvv.y;
        o.z = acc[p][q][i][2] + bvv.z;
        o.w = acc[p][q][i][3] + bvv.w;
        if (EPI == 2) {
          o.x = gelu_f(o.x); o.y = gelu_f(o.y);
          o.z = gelu_f(o.z); o.w = gelu_f(o.w);
        }
        if (EPI == 1) {
          const float* Rrow = res + gr * N + n0;
          float4 rv = *(const float4*)&Rrow[cidx];
          o.x += rv.x; o.y += rv.y; o.z += rv.z; o.w += rv.w;
        }
        *(float4*)&Crow[cidx] = o;
      }
    }
  }
}

template <int EPI>
__global__ __launch_bounds__(256) void gemm_k(const float* __restrict__ A,
                                              const float* __restrict__ Bw,
                                              const float* __restrict__ bias,
                                              const float* __restrict__ res,
                                              float* __restrict__ C,
                                              int M, int N, int K) {
  __shared__ float As[BK][LDT];
  __shared__ float Bs[BK][LDT];
  gemm_body<EPI>(A, Bw, bias, res, C, M, N, K,
                 blockIdx.y * 128, blockIdx.x * 128, As, Bs);
}

__global__ __launch_bounds__(256) void qkv_k(const float* __restrict__ A,
                                             const float* __restrict__ wq,
                                             const float* __restrict__ wk,
                                             const float* __restrict__ wv,
                                             const float* __restrict__ bq,
                                             const float* __restrict__ bk,
                                             const float* __restrict__ bv,
                                             float* __restrict__ qo,
                                             float* __restrict__ ko,
                                             float* __restrict__ vo) {
  __shared__ float As[BK][LDT];
  __shared__ float Bs[BK][LDT];
  int which = blockIdx.x >> 3;
  int n0 = (blockIdx.x & 7) * 128;
  const float* Bw = (which == 0) ? wq : (which == 1) ? wk : wv;
  const float* bias = (which == 0) ? bq : (which == 1) ? bk : bv;
  float* C = (which == 0) ? qo : (which == 1) ? ko : vo;
  gemm_body<0>(A, Bw, bias, nullptr, C, MM, CC, CC, blockIdx.y * 128, n0, As, Bs);
}

__global__ __launch_bounds__(256) void attn_k(const float* __restrict__ q,
                                              const float* __restrict__ k,
                                              const float* __restrict__ v,
                                              float* __restrict__ yf) {
  __shared__ float Qs[64][65];
  __shared__ float KPs[64][65];
  __shared__ float Vs[64][64];

  int tid = threadIdx.x;
  int tx = tid & 15, ty = tid >> 4;
  int qb = blockIdx.x;
  int bh = blockIdx.y;
  int b = bh >> 4;
  int h = bh & 15;
  int q0 = qb * 64;

  const float* qbase = q + (size_t)b * TT * CC + (size_t)h * DHH;
  const float* kbase = k + (size_t)b * TT * CC + (size_t)h * DHH;
  const float* vbase = v + (size_t)b * TT * CC + (size_t)h * DHH;

#pragma unroll
  for (int i = 0; i < 4; ++i) {
    int r = ty + 16 * i;
    float4 t = *(const float4*)(qbase + (size_t)(q0 + r) * CC + tx * 4);
    Qs[r][tx * 4 + 0] = t.x; Qs[r][tx * 4 + 1] = t.y;
    Qs[r][tx * 4 + 2] = t.z; Qs[r][tx * 4 + 3] = t.w;
  }

  float mrun[4], lrun[4], accO[4][4];
#pragma unroll
  for (int i = 0; i < 4; ++i) {
    mrun[i] = -1e30f; lrun[i] = 0.0f;
#pragma unroll
    for (int j = 0; j < 4; ++j) accO[i][j] = 0.0f;
  }

  int kbmax = qb + 1; if (kbmax > (TT / 64 - 1)) kbmax = TT / 64 - 1;
  for (int kb = 0; kb <= kbmax; ++kb) {
    int k0 = kb * 64;
    __syncthreads();
#pragma unroll
    for (int i = 0; i < 4; ++i) {
      int r = ty + 16 * i;
      float4 tk = *(const float4*)(kbase + (size_t)(k0 + r) * CC + tx * 4);
      KPs[r][tx * 4 + 0] = tk.x; KPs[r][tx * 4 + 1] = tk.y;
      KPs[r][tx * 4 + 2] = tk.z; KPs[r][tx * 4 + 3] = tk.w;
      float4 tv = *(const float4*)(vbase + (size_t)(k0 + r) * CC + tx * 4);
      *(float4*)&Vs[r][tx * 4] = tv;
    }
    __syncthreads();

    float s[4][4] = {};
    for (int d = 0; d < 64; ++d) {
      float qv[4], kv[4];
#pragma unroll
      for (int i = 0; i < 4; ++i) qv[i] = Qs[ty * 4 + i][d];
#pragma unroll
      for (int j = 0; j < 4; ++j) kv[j] = KPs[tx * 4 + j][d];
#pragma unroll
      for (int i = 0; i < 4; ++i)
#pragma unroll
        for (int j = 0; j < 4; ++j)
          s[i][j] = fmaf(qv[i], kv[j], s[i][j]);
    }
#pragma unroll
    for (int i = 0; i < 4; ++i) {
      int gi = q0 + ty * 4 + i;
#pragma unroll
      for (int j = 0; j < 4; ++j) {
        int gj = k0 + tx * 4 + j;
        bool keep = (gj <= gi) ||
                    ((gi < TT - 1) && (gi / 10 == gj / 10) && (gj % 10 <= 8));
        s[i][j] = keep ? s[i][j] * 0.125f : -1e30f;
      }
    }
    __syncthreads();

#pragma unroll
    for (int i = 0; i < 4; ++i) {
      float mloc = fmaxf(fmaxf(s[i][0], s[i][1]), fmaxf(s[i][2], s[i][3]));
#pragma unroll
      for (int m = 1; m < 16; m <<= 1) mloc = fmaxf(mloc, __shfl_xor(mloc, m, 64));
      float mnew = fmaxf(mrun[i], mloc);
      float p0 = __expf(s[i][0] - mnew);
      float p1 = __expf(s[i][1] - mnew);
      float p2 = __expf(s[i][2] - mnew);
      float p3 = __expf(s[i][3] - mnew);
      float psum = p0 + p1 + p2 + p3;
#pragma unroll
      for (int m = 1; m < 16; m <<= 1) psum += __shfl_xor(psum, m, 64);
      float alpha = __expf(mrun[i] - mnew);
      lrun[i] = lrun[i] * alpha + psum;
      mrun[i] = mnew;
#pragma unroll
      for (int j = 0; j < 4; ++j) accO[i][j] *= alpha;
      KPs[ty * 4 + i][tx * 4 + 0] = p0;
      KPs[ty * 4 + i][tx * 4 + 1] = p1;
      KPs[ty * 4 + i][tx * 4 + 2] = p2;
      KPs[ty * 4 + i][tx * 4 + 3] = p3;
    }
    __syncthreads();

    for (int cidx = 0; cidx < 64; ++cidx) {
      float pr[4];
#pragma unroll
      for (int i = 0; i < 4; ++i) pr[i] = KPs[ty * 4 + i][cidx];
      float4 vv = *(const float4*)&Vs[cidx][tx * 4];
      float vb4[4] = {vv.x, vv.y, vv.z, vv.w};
#pragma unroll
      for (int i = 0; i < 4; ++i)
#pragma unroll
        for (int j = 0; j < 4; ++j)
          accO[i][j] = fmaf(pr[i], vb4[j], accO[i][j]);
    }
  }

#pragma unroll
  for (int i = 0; i < 4; ++i) {
    float inv = 1.0f / lrun[i];
    float4 o;
    o.x = accO[i][0] * inv; o.y = accO[i][1] * inv;
    o.z = accO[i][2] * inv; o.w = accO[i][3] * inv;
    *(float4*)(yf + (size_t)(b * TT + q0 + ty * 4 + i) * CC + h * DHH + tx * 4) = o;
  }
}

// ---------------------------------------------------------------------------
extern "C" void kernel_launch(void* const* d_in, const int* in_sizes, int n_in,
                              void* d_out, int out_size, void* d_ws, size_t ws_size,
                              hipStream_t stream) {
  (void)in_sizes; (void)n_in; (void)out_size;
  const float* x    = (const float*)d_in[0];
  const float* ln1w = (const float*)d_in[1];
  const float* ln1b = (const float*)d_in[2];
  const float* ln2w = (const float*)d_in[3];
  const float* ln2b = (const float*)d_in[4];
  const float* wq   = (const float*)d_in[5];
  const float* bq   = (const float*)d_in[6];
  const float* wk   = (const float*)d_in[7];
  const float* bk   = (const float*)d_in[8];
  const float* wv   = (const float*)d_in[9];
  const float* bv   = (const float*)d_in[10];
  const float* wo   = (const float*)d_in[11];
  const float* bo   = (const float*)d_in[12];
  const float* w1   = (const float*)d_in[13];
  const float* b1   = (const float*)d_in[14];
  const float* w2   = (const float*)d_in[15];
  const float* b2   = (const float*)d_in[16];
  float* out = (float*)d_out;

  const size_t SZ = (size_t)MM * CC;
  hipMemcpyAsync(out, x, SZ * sizeof(float), hipMemcpyDeviceToDevice, stream);

  const size_t MB = 1024 * 1024;
  if (ws_size >= 112 * MB) {
    // ------------------- split-bf16 MFMA path -------------------
    unsigned short* u = (unsigned short*)d_ws;
    const size_t Mu = 1024 * 1024;
    unsigned short* wqh = u;            unsigned short* wql = u + 1 * Mu;
    unsigned short* wkh = u + 2 * Mu;   unsigned short* wkl = u + 3 * Mu;
    unsigned short* wvh = u + 4 * Mu;   unsigned short* wvl = u + 5 * Mu;
    unsigned short* woh = u + 6 * Mu;   unsigned short* wol = u + 7 * Mu;
    unsigned short* w1h = u + 8 * Mu;   unsigned short* w1l = u + 12 * Mu;
    unsigned short* w2h = u + 16 * Mu;  unsigned short* w2l = u + 20 * Mu;
    unsigned short* hh  = u + 24 * Mu;  unsigned short* hl  = u + 28 * Mu;
    unsigned short* qhp = u + 32 * Mu;  unsigned short* qlp = u + 36 * Mu;
    unsigned short* khp = u + 40 * Mu;  unsigned short* klp = u + 44 * Mu;
    unsigned short* vth = u + 48 * Mu;  unsigned short* vtl = u + 52 * Mu;
    unsigned short* hidh;
    unsigned short* hidl;
    int nch;
    if (ws_size >= 176 * MB) {
      hidh = u + 56 * Mu;   // 4096x4096 u16
      hidl = u + 72 * Mu;
      nch = 1;
    } else {
      hidh = qhp;           // q/k dead during MLP; 2 chunks of 2048 rows
      hidl = qhp + 8 * Mu;
      nch = 2;
    }
    int mch = MM / nch;

    for (int l = 0; l < LL; ++l) {
      SplitArgs sa;
      sa.src[0] = wq + (size_t)l * CC * CC;  sa.dh[0] = wqh; sa.dl[0] = wql;
      sa.src[1] = wk + (size_t)l * CC * CC;  sa.dh[1] = wkh; sa.dl[1] = wkl;
      sa.src[2] = wv + (size_t)l * CC * CC;  sa.dh[2] = wvh; sa.dl[2] = wvl;
      sa.src[3] = wo + (size_t)l * CC * CC;  sa.dh[3] = woh; sa.dl[3] = wol;
      sa.src[4] = w1 + (size_t)l * CC * FFF; sa.dh[4] = w1h; sa.dl[4] = w1l;
      sa.src[5] = w2 + (size_t)l * FFF * CC; sa.dh[5] = w2h; sa.dl[5] = w2l;
      splitT_k<<<3072, 256, 0, stream>>>(sa);

      ln_k<1><<<MM, 256, 0, stream>>>(out, ln1w + (size_t)l * CC, ln1b + (size_t)l * CC,
                                      nullptr, hh, hl);
      sqkv_k<<<dim3(24, MM / 128), 256, 0, stream>>>(
          hh, hl, wqh, wql, wkh, wkl, wvh, wvl,
          bq + (size_t)l * CC, bk + (size_t)l * CC, bv + (size_t)l * CC,
          qhp, qlp, khp, klp, vth, vtl);
      mattn_k<<<dim3(TT / 64, BB * HH), 256, 0, stream>>>(
          qhp, qlp, khp, klp, vth, vtl, hh, hl);
      sgemm_k<1><<<dim3(CC / 128, MM / 128), 256, 0, stream>>>(
          hh, hl, woh, wol, bo + (size_t)l * CC, out, out, nullptr, nullptr, MM, CC, CC);
      ln_k<1><<<MM, 256, 0, stream>>>(out, ln2w + (size_t)l * CC, ln2b + (size_t)l * CC,
                                      nullptr, hh, hl);
      for (int c = 0; c < nch; ++c) {
        size_t aoff = (size_t)c * mch * CC;
        sgemm_k<2><<<dim3(FFF / 128, mch / 128), 256, 0, stream>>>(
            hh + aoff, hl + aoff, w1h, w1l, b1 + (size_t)l * FFF, nullptr,
            nullptr, hidh, hidl, mch, FFF, CC);
        sgemm_k<1><<<dim3(CC / 128, mch / 128), 256, 0, stream>>>(
            hidh, hidl, w2h, w2l, b2 + (size_t)l * CC, out + aoff,
            out + aoff, nullptr, nullptr, mch, CC, FFF);
      }
    }
  } else {
    // ------------------- fp32 fallback path (verified round 2) ------------
    float* hbuf = (float*)d_ws;
    float* qbuf = hbuf + SZ;
    float* kbuf = qbuf + SZ;
    float* vbuf = kbuf + SZ;
    float* hid;
    int nch;
    if (ws_size >= (4 * SZ + (size_t)MM * FFF) * sizeof(float)) {
      hid = vbuf + SZ; nch = 1;
    } else {
      hid = qbuf; nch = 2;
    }
    int mch = MM / nch;
    dim3 gProj(CC / 128, MM / 128);
    for (int l = 0; l < LL; ++l) {
      const float* wq_l = wq + (size_t)l * CC * CC;
      const float* wk_l = wk + (size_t)l * CC * CC;
      const float* wv_l = wv + (size_t)l * CC * CC;
      const float* wo_l = wo + (size_t)l * CC * CC;
      const float* w1_l = w1 + (size_t)l * CC * FFF;
      const float* w2_l = w2 + (size_t)l * FFF * CC;
      ln_k<0><<<MM, 256, 0, stream>>>(out, ln1w + (size_t)l * CC, ln1b + (size_t)l * CC,
                                      hbuf, nullptr, nullptr);
      qkv_k<<<dim3(24, MM / 128), 256, 0, stream>>>(
          hbuf, wq_l, wk_l, wv_l,
          bq + (size_t)l * CC, bk + (size_t)l * CC, bv + (size_t)l * CC,
          qbuf, kbuf, vbuf);
      attn_k<<<dim3(TT / 64, BB * HH), 256, 0, stream>>>(qbuf, kbuf, vbuf, hbuf);
      gemm_k<1><<<gProj, 256, 0, stream>>>(hbuf, wo_l, bo + (size_t)l * CC, out, out, MM, CC, CC);
      ln_k<0><<<MM, 256, 0, stream>>>(out, ln2w + (size_t)l * CC, ln2b + (size_t)l * CC,
                                      hbuf, nullptr, nullptr);
      for (int c = 0; c < nch; ++c) {
        const float* aoff = hbuf + (size_t)c * mch * CC;
        float* ooff = out + (size_t)c * mch * CC;
        gemm_k<2><<<dim3(FFF / 128, mch / 128), 256, 0, stream>>>(
            aoff, w1_l, b1 + (size_t)l * FFF, nullptr, hid, mch, FFF, CC);
        gemm_k<1><<<dim3(CC / 128, mch / 128), 256, 0, stream>>>(
            hid, w2_l, b2 + (size_t)l * CC, ooff, ooff, mch, CC, FFF);
      }
    }
  }
}